// Round 5
// baseline (864.091 us; speedup 1.0000x reference)
//
#include <hip/hip_runtime.h>
#include <hip/hip_cooperative_groups.h>
#include <hip/hip_bf16.h>
#include <cstdint>

namespace cg = cooperative_groups;

// Problem constants
#define T_  4
#define B_  32
#define C_  384
#define HF_ 1536
#define HW_ 196
#define E_  8
#define N_  128
#define REC_CAP 16384
#define GRID_ 1024
#define NROW 1792          // (n,h) units
#define NGT  50176         // (pair, position) gather tasks = 256*196
#define LCAP 64            // spike-list capacity per (pair,pos); P(nnz>64) ~ 1e-15

struct Params {
  const float *x, *rw, *rb, *rg, *rbeta, *rmean, *rvar;
  const float *w1, *b1, *g1, *be1, *m1, *v1;
  const float *w2, *b2, *g2, *be2, *m2, *v2, *taus;
  float* out; float* aux_out;
  int* header;            // [0]=rec_count [8..15]=f_acc [16..23]=p_acc
  float *f_acc, *p_acc;
  float* cnt; int* sel_e; float* sel_g; float* gsum; float* K;
  float *A, *Bc, *const2, *inv2v;
  int* rec;
  __hip_bfloat16* w1t;
  int* nnzarr;            // [NGT]
  unsigned short* list16; // [NGT * LCAP]
};

__device__ __forceinline__ void acc24(uint4 u0, uint4 u1, uint4 u2, float* acc) {
  uint32_t us[12] = {u0.x, u0.y, u0.z, u0.w, u1.x, u1.y, u1.z, u1.w,
                     u2.x, u2.y, u2.z, u2.w};
  #pragma unroll
  for (int d = 0; d < 12; ++d) {
    acc[2 * d]     += __uint_as_float(us[d] << 16);
    acc[2 * d + 1] += __uint_as_float(us[d] & 0xffff0000u);
  }
}

// phases: 1=prep+lif+transpose 2=router 3=lists+combine 4=gather 5=apply
__global__ __launch_bounds__(256, 4) void k_mega(Params p, int pmin, int pmax) {
  __shared__ __align__(16) char smem[21568];
  __shared__ int s_i1, s_i2;
  __shared__ float s_g1, s_g2;
  int bid = blockIdx.x, tid = threadIdx.x;
  int lane = tid & 63, wave = tid >> 6;
  bool multi = pmin < pmax;

  // ============ Phase 1: prep + LIF + w1 transpose(bf16) ============
  if (pmin <= 1 && 1 <= pmax) {
    {
      int idx = bid * 256 + tid;
      if (idx < 64) p.header[idx] = 0;
      if (idx < E_ * HF_) {
        int e = idx / HF_;
        float inv = p.g1[idx] / sqrtf(p.v1[idx] + 1e-5f);
        float sh  = p.be1[idx] - p.m1[idx] * inv;
        p.A[idx]  = inv;
        p.Bc[idx] = inv * p.b1[idx] + sh - p.taus[e];
      }
      if (idx < E_ * C_) {
        float inv = p.g2[idx] / sqrtf(p.v2[idx] + 1e-5f);
        p.const2[idx] = p.b2[idx] * inv + (p.be2[idx] - p.m2[idx] * inv);
        p.inv2v[idx]  = inv;
      }
    }
    // LIF: one wave per (b,c)
    for (int bc = bid * 4 + wave; bc < B_ * C_; bc += GRID_ * 4) {
      size_t base = (size_t)bc * HW_;
      float v0 = 0.f, v1 = 0.f, v2 = 0.f, v3 = 0.f;
      int pk = 0;
      #pragma unroll
      for (int t = 0; t < T_; ++t) {
        const float* xt = p.x + (size_t)t * (B_ * C_ * HW_) + base;
        float a0 = xt[lane];
        float a1 = xt[lane + 64];
        float a2 = xt[lane + 128];
        float a3 = (lane < 4) ? xt[192 + lane] : -1e30f;
        int c = 0;
        v0 = v0 + (a0 - v0) * 0.5f; if (v0 - 1.0f >= 0.0f) { c++; v0 = 0.f; }
        v1 = v1 + (a1 - v1) * 0.5f; if (v1 - 1.0f >= 0.0f) { c++; v1 = 0.f; }
        v2 = v2 + (a2 - v2) * 0.5f; if (v2 - 1.0f >= 0.0f) { c++; v2 = 0.f; }
        v3 = v3 + (a3 - v3) * 0.5f; if (v3 - 1.0f >= 0.0f) { c++; v3 = 0.f; }
        pk += c << (8 * t);
      }
      #pragma unroll
      for (int off = 1; off < 64; off <<= 1) pk += __shfl_xor(pk, off, 64);
      if (lane == 0) {
        #pragma unroll
        for (int t = 0; t < T_; ++t)
          p.cnt[(size_t)t * (B_ * C_) + bc] = (float)((pk >> (8 * t)) & 255);
      }
    }
    // transpose w1 -> bf16 w1t
    float (*tile)[33] = (float(*)[33])smem;
    for (int tl = bid; tl < E_ * 288; tl += GRID_) {
      int e = tl / 288, r2 = tl % 288;
      int c0 = (r2 / 24) * 32, o0 = (r2 % 24) * 64;
      int cl = tid & 31, olb = tid >> 5;
      __syncthreads();
      #pragma unroll
      for (int it = 0; it < 8; ++it) {
        int ol = olb + it * 8;
        tile[ol & 63][cl] = p.w1[(size_t)(e * HF_ + o0 + ol) * C_ + c0 + cl];
      }
      __syncthreads();
      int ol2 = tid & 63, clb = tid >> 6;
      #pragma unroll
      for (int it = 0; it < 8; ++it) {
        int cl2 = clb + it * 4;
        p.w1t[(size_t)(e * C_ + c0 + cl2) * HF_ + o0 + ol2] =
            __float2bfloat16(tile[ol2][cl2]);
      }
    }
  }
  if (multi) cg::this_grid().sync();

  // ============ Phase 2: router ============
  if (pmin <= 2 && 2 <= pmax && bid < N_) {
    int n = bid;
    float* sc   = (float*)smem;        // 384
    float* part = sc + C_;             // 256
    float* lg   = part + 256;          // 8
    for (int c = tid; c < C_; c += 256) sc[c] = p.cnt[(size_t)n * C_ + c];
    __syncthreads();
    {
      int e = tid >> 5, sub = tid & 31;
      float d = 0.f;
      for (int c = sub; c < C_; c += 32) d += p.rw[e * C_ + c] * sc[c];
      part[tid] = d;
    }
    __syncthreads();
    if (tid < E_) {
      float dot = 0.f;
      #pragma unroll
      for (int j = 0; j < 32; ++j) dot += part[tid * 32 + j];
      float inv = p.rg[tid] / sqrtf(p.rvar[tid] + 1e-5f);
      lg[tid] = (dot * (1.0f / HW_) + p.rb[tid]) * inv +
                (p.rbeta[tid] - p.rmean[tid] * inv);
    }
    __syncthreads();
    if (tid == 0) {
      float m = lg[0];
      for (int e = 1; e < E_; ++e) m = fmaxf(m, lg[e]);
      float pr[E_]; float s = 0.f;
      for (int e = 0; e < E_; ++e) { pr[e] = expf(lg[e] - m); s += pr[e]; }
      float invs = 1.0f / s;
      for (int e = 0; e < E_; ++e) pr[e] *= invs;
      int i1 = 0;
      for (int e = 1; e < E_; ++e) if (pr[e] > pr[i1]) i1 = e;
      int i2 = (i1 == 0) ? 1 : 0;
      for (int e = 0; e < E_; ++e) if (e != i1 && pr[e] > pr[i2]) i2 = e;
      float w = pr[i1] + pr[i2];
      float ga = pr[i1] / w, gb = pr[i2] / w;
      p.sel_e[2 * n] = i1; p.sel_e[2 * n + 1] = i2;
      p.sel_g[2 * n] = ga; p.sel_g[2 * n + 1] = gb;
      p.gsum[n] = ga + gb;
      s_i1 = i1; s_i2 = i2; s_g1 = ga; s_g2 = gb;
      atomicAdd(&p.f_acc[i1], 1.0f);
      atomicAdd(&p.f_acc[i2], 1.0f);
      for (int e = 0; e < E_; ++e) atomicAdd(&p.p_acc[e], pr[e]);
    }
    __syncthreads();
    int i1 = s_i1, i2 = s_i2; float ga = s_g1, gb = s_g2;
    for (int c = tid; c < C_; c += 256)
      p.K[(size_t)n * C_ + c] =
          ga * p.const2[i1 * C_ + c] + gb * p.const2[i2 * C_ + c];
  }
  if (multi) cg::this_grid().sync();

  // ============ Phase 3: spike-list build + fused combine ============
  if (pmin <= 3 && 3 <= pmax) {
    float* xs = (float*)smem;                       // xs[w*385 + c]
    unsigned long long lmask = (1ull << lane) - 1ull;
    for (int u = bid; u < NROW; u += GRID_) {
      int n = u / 14, h = u - n * 14;
      __syncthreads();  // protect xs from previous iteration's readers
      for (int idx = tid; idx < C_ * 7; idx += 256) {
        int c = idx / 7, wp = idx - c * 7;
        float2 v = *(const float2*)(p.x + ((size_t)(n * C_ + c) * 14 + h) * 14 + 2 * wp);
        xs[(2 * wp) * 385 + c]     = v.x;
        xs[(2 * wp + 1) * 385 + c] = v.y;
      }
      __syncthreads();

      for (int t = wave; t < 28; t += 4) {
        int k = t / 14, w = t - k * 14;
        int pair = 2 * n + k;
        float tau = p.taus[p.sel_e[pair]];
        size_t lbase = (size_t)(pair * 196 + h * 14 + w) * LCAP;
        int nnz = 0;
        #pragma unroll
        for (int cb = 0; cb < 6; ++cb) {
          int c = cb * 64 + lane;
          bool sp = (xs[w * 385 + c] / tau - 1.0f >= 0.0f);  // s1 spike
          unsigned long long m = __ballot(sp);
          int pos = nnz + __popcll(m & lmask);
          if (sp && pos < LCAP) p.list16[lbase + pos] = (unsigned short)c;
          nnz += __popcll(m);
        }
        if (lane == 0) p.nnzarr[pair * 196 + h * 14 + w] = nnz < LCAP ? nnz : LCAP;
      }

      // fused combine: out = gsum*x + K
      float g = p.gsum[n];
      const float* Kn = p.K + (size_t)n * C_;
      for (int idx = tid; idx < C_ * 7; idx += 256) {
        int c = idx / 7, wp = idx - c * 7;
        float kc = Kn[c];
        float2 v;
        v.x = g * xs[(2 * wp) * 385 + c] + kc;
        v.y = g * xs[(2 * wp + 1) * 385 + c] + kc;
        *(float2*)(p.out + ((size_t)(n * C_ + c) * 14 + h) * 14 + 2 * wp) = v;
      }
    }
  }
  if (multi) cg::this_grid().sync();

  // ============ Phase 4: gather (one wave per (pair,pos), no LDS) ============
  if (pmin <= 4 && 4 <= pmax) {
    for (int tw = bid * 4 + wave; tw < NGT; tw += GRID_ * 4) {
      int pair = tw / 196, pos = tw - pair * 196;
      int e = p.sel_e[pair];
      int nnz = p.nnzarr[tw];
      int lv = (int)p.list16[(size_t)tw * LCAP + lane];  // my list entry
      const uint4* wb = (const uint4*)(p.w1t + (size_t)e * C_ * HF_);
      float acc[24];
      #pragma unroll
      for (int q = 0; q < 24; ++q) acc[q] = 0.f;

      int j = 0;
      for (; j + 4 <= nnz; j += 4) {              // 12 dwordx4 in flight
        int c0 = __shfl(lv, j + 0);
        int c1 = __shfl(lv, j + 1);
        int c2 = __shfl(lv, j + 2);
        int c3 = __shfl(lv, j + 3);
        const uint4* r0 = wb + c0 * 192 + lane * 3;
        const uint4* r1 = wb + c1 * 192 + lane * 3;
        const uint4* r2 = wb + c2 * 192 + lane * 3;
        const uint4* r3 = wb + c3 * 192 + lane * 3;
        uint4 a0 = r0[0], a1 = r0[1], a2 = r0[2];
        uint4 b0 = r1[0], b1 = r1[1], b2 = r1[2];
        uint4 cc0 = r2[0], cc1 = r2[1], cc2 = r2[2];
        uint4 d0 = r3[0], d1 = r3[1], d2 = r3[2];
        acc24(a0, a1, a2, acc);
        acc24(b0, b1, b2, acc);
        acc24(cc0, cc1, cc2, acc);
        acc24(d0, d1, d2, acc);
      }
      for (; j < nnz; ++j) {
        int c0 = __shfl(lv, j);
        const uint4* r0 = wb + c0 * 192 + lane * 3;
        uint4 a0 = r0[0], a1 = r0[1], a2 = r0[2];
        acc24(a0, a1, a2, acc);
      }

      const float4* Af = (const float4*)(p.A + e * HF_) + lane * 6;
      const float4* Bf = (const float4*)(p.Bc + e * HF_) + lane * 6;
      #pragma unroll
      for (int q4 = 0; q4 < 6; ++q4) {
        float4 Av = Af[q4];
        float4 Bv = Bf[q4];
        float a0 = Av.x * acc[q4 * 4 + 0] + Bv.x;
        float a1 = Av.y * acc[q4 * 4 + 1] + Bv.y;
        float a2 = Av.z * acc[q4 * 4 + 2] + Bv.z;
        float a3 = Av.w * acc[q4 * 4 + 3] + Bv.w;
        #pragma unroll
        for (int qi = 0; qi < 4; ++qi) {
          float av = (qi == 0) ? a0 : (qi == 1) ? a1 : (qi == 2) ? a2 : a3;
          if (av >= 0.0f) {                        // layer-2 spike (rare)
            int ridx = atomicAdd(&p.header[0], 1);
            if (ridx < REC_CAP) {
              p.rec[ridx * 3 + 0] = pair;
              p.rec[ridx * 3 + 1] = pos;
              p.rec[ridx * 3 + 2] = lane * 24 + q4 * 4 + qi;
            }
          }
        }
      }
    }
  }
  if (multi) cg::this_grid().sync();

  // ============ Phase 5: apply records + aux ============
  if (pmin <= 5 && 5 <= pmax) {
    int nrec = p.header[0];
    if (nrec > REC_CAP) nrec = REC_CAP;
    for (int r = bid; r < nrec; r += GRID_) {
      int pair = p.rec[r * 3], pos = p.rec[r * 3 + 1], o = p.rec[r * 3 + 2];
      int n = pair >> 1;
      int e = p.sel_e[pair];
      float g = p.sel_g[pair];
      for (int c = tid; c < C_; c += 256) {
        float wv = p.w2[(size_t)(e * C_ + c) * HF_ + o];
        atomicAdd(&p.out[(size_t)(n * C_ + c) * HW_ + pos],
                  g * p.inv2v[e * C_ + c] * wv);
      }
    }
    if (bid == 0 && tid == 0) {
      float s = 0.f;
      for (int e = 0; e < E_; ++e)
        s += (p.f_acc[e] * (1.0f / N_)) * (p.p_acc[e] * (1.0f / N_));
      *p.aux_out = 0.01f * E_ * s;
    }
  }
}

extern "C" void kernel_launch(void* const* d_in, const int* in_sizes, int n_in,
                              void* d_out, int out_size, void* d_ws, size_t ws_size,
                              hipStream_t stream) {
  Params prm;
  prm.x     = (const float*)d_in[0];
  prm.rw    = (const float*)d_in[1];
  prm.rb    = (const float*)d_in[2];
  prm.rg    = (const float*)d_in[3];
  prm.rbeta = (const float*)d_in[4];
  prm.rmean = (const float*)d_in[5];
  prm.rvar  = (const float*)d_in[6];
  prm.w1    = (const float*)d_in[7];
  prm.b1    = (const float*)d_in[8];
  prm.g1    = (const float*)d_in[9];
  prm.be1   = (const float*)d_in[10];
  prm.m1    = (const float*)d_in[11];
  prm.v1    = (const float*)d_in[12];
  prm.w2    = (const float*)d_in[13];
  prm.b2    = (const float*)d_in[14];
  prm.g2    = (const float*)d_in[15];
  prm.be2   = (const float*)d_in[16];
  prm.m2    = (const float*)d_in[17];
  prm.v2    = (const float*)d_in[18];
  prm.taus  = (const float*)d_in[19];
  prm.out   = (float*)d_out;
  prm.aux_out = (float*)d_out + (out_size - 1);

  char* ws = (char*)d_ws;
  prm.header = (int*)ws;
  prm.f_acc  = (float*)ws + 8;
  prm.p_acc  = (float*)ws + 16;
  prm.cnt    = (float*)(ws + 256);
  prm.sel_e  = (int*)(ws + 196864);
  prm.sel_g  = (float*)(ws + 197888);
  prm.gsum   = (float*)(ws + 198912);
  prm.K      = (float*)(ws + 199424);
  prm.A      = (float*)(ws + 396032);
  prm.Bc     = (float*)(ws + 445184);
  prm.const2 = (float*)(ws + 494336);
  prm.inv2v  = (float*)(ws + 506624);
  prm.rec    = (int*)(ws + 518912);
  prm.w1t    = (__hip_bfloat16*)(ws + 715520);
  prm.nnzarr = (int*)(ws + 10152704);              // 50176*4   = 200704 B
  prm.list16 = (unsigned short*)(ws + 10353408);   // 50176*64*2 = 6422528 B

  int lo = 1, hi = 5;
  void* args[] = {&prm, &lo, &hi};
  hipError_t err = hipLaunchCooperativeKernel((const void*)k_mega,
                                              dim3(GRID_), dim3(256),
                                              args, 0, stream);
  if (err != hipSuccess) {
    for (int ph = 1; ph <= 5; ++ph) {
      k_mega<<<GRID_, 256, 0, stream>>>(prm, ph, ph);
    }
  }
}

// Round 6
// 233.246 us; speedup vs baseline: 3.7046x; 3.7046x over previous
//
#include <hip/hip_runtime.h>
#include <hip/hip_bf16.h>
#include <cstdint>
#include <math.h>

// Problem constants
#define T_  4
#define B_  32
#define C_  384
#define HF_ 1536
#define HW_ 196
#define E_  8
#define N_  128
#define REC_CAP 16384
#define NROW 1792          // (n,h) units
#define NGT  50176         // (pair,pos) gather tasks = 256*196
#define LCAP 64

#define LIFB (B_ * C_)        // 12288
#define TRB  (E_ * 12 * 24)   // 2304 transpose tiles
#define PRB  48

// ---------------------------------------------------------------------------
// K1: LIF spike counts + BN-const folding + w1 transpose->bf16 + rowmax partials
// ---------------------------------------------------------------------------
__global__ __launch_bounds__(256) void k_lifprep(
    const float* __restrict__ x, float* __restrict__ cnt,
    const float* __restrict__ w1, __hip_bfloat16* __restrict__ w1t,
    const float* b1, const float* g1, const float* be1,
    const float* m1, const float* v1,
    const float* b2, const float* g2, const float* be2,
    const float* m2, const float* v2,
    const float* taus,
    float* A, float* Bc, float* const2, float* inv2v,
    float* rowmaxp, int* header) {
  __shared__ float tile[64][33];
  __shared__ int c4[T_];
  int blk = blockIdx.x;
  int tid = threadIdx.x;

  if (blk < LIFB) {
    // ---- LIF ----
    if (tid < T_) c4[tid] = 0;
    __syncthreads();
    int bc = blk;
    bool act = tid < HW_;
    float v = 0.f;
    size_t base = (size_t)bc * HW_ + (act ? tid : 0);
    #pragma unroll
    for (int t = 0; t < T_; ++t) {
      float xv = act ? x[base + (size_t)t * B_ * C_ * HW_] : -1e30f;
      v = v + (xv - v) * 0.5f;                 // tau=2.0
      bool sp = (v - 1.0f >= 0.0f);
      if (sp) v = 0.f;
      unsigned long long m = __ballot(act && sp);
      if ((tid & 63) == 0) atomicAdd(&c4[t], __popcll(m));
    }
    __syncthreads();
    if (tid < T_) cnt[(size_t)tid * B_ * C_ + bc] = (float)c4[tid];
  } else if (blk < LIFB + TRB) {
    // ---- transpose w1 -> bf16 w1t + rowmax partials ----
    int rem = blk - LIFB;
    int e = rem / 288, r2 = rem % 288;
    int ct = r2 / 24, ot = r2 % 24;
    int c0 = ct * 32, o0 = ot * 64;
    int cl = tid & 31, olb = tid >> 5;
    #pragma unroll
    for (int it = 0; it < 8; ++it) {
      int ol = olb + it * 8;
      tile[ol][cl] = w1[(size_t)(e * HF_ + o0 + ol) * C_ + c0 + cl];
    }
    __syncthreads();
    int ol2 = tid & 63, clb = tid >> 6;
    #pragma unroll
    for (int it = 0; it < 8; ++it) {
      int cl2 = clb + it * 4;
      w1t[(size_t)(e * C_ + c0 + cl2) * HF_ + o0 + ol2] =
          __float2bfloat16(tile[ol2][cl2]);
    }
    // per-(c, ot) max |bf16(w1)| over this tile's 64 outputs (race-free partials)
    if (tid < 32) {
      float m = 0.f;
      for (int ol = 0; ol < 64; ++ol) {
        float bv = __bfloat162float(__float2bfloat16(tile[ol][tid]));
        m = fmaxf(m, fabsf(bv));
      }
      rowmaxp[(size_t)(e * C_ + c0 + tid) * 24 + ot] = m;
    }
  } else {
    // ---- prep ----
    int idx = (blk - LIFB - TRB) * 256 + tid;
    if (idx < 64) header[idx] = 0;
    if (idx < E_ * HF_) {
      int e = idx / HF_;
      float inv = g1[idx] / sqrtf(v1[idx] + 1e-5f);
      float sh  = be1[idx] - m1[idx] * inv;
      A[idx]  = inv;
      Bc[idx] = inv * b1[idx] + sh - taus[e];
    }
    if (idx < E_ * C_) {
      float inv = g2[idx] / sqrtf(v2[idx] + 1e-5f);
      const2[idx] = b2[idx] * inv + (be2[idx] - m2[idx] * inv);
      inv2v[idx]  = inv;
    }
  }
}

// ---------------------------------------------------------------------------
// K2: router (blocks 0..N-1) + rowmax reduce (N..N+11) + thrmin (N+12)
// ---------------------------------------------------------------------------
__global__ __launch_bounds__(256) void k_router(
    const float* __restrict__ cnt, const float* __restrict__ rw,
    const float* rb, const float* rg, const float* rbeta,
    const float* rmean, const float* rvar,
    const float* __restrict__ const2,
    const float* __restrict__ rowmaxp, float* __restrict__ rowmax,
    const float* __restrict__ A, const float* __restrict__ Bc,
    float* __restrict__ thrmin,
    int* sel_e, float* sel_g, float* gsum, float* K,
    float* f_acc, float* p_acc) {
  __shared__ float sc[C_ + 256 + E_];
  __shared__ int s_i1, s_i2;
  __shared__ float s_g1, s_g2;
  int bid = blockIdx.x, tid = threadIdx.x;

  if (bid < N_) {
    int n = bid;
    float* part = sc + C_;
    float* lg = part + 256;
    for (int c = tid; c < C_; c += 256) sc[c] = cnt[(size_t)n * C_ + c];
    __syncthreads();
    {
      int e = tid >> 5, sub = tid & 31;
      float d = 0.f;
      for (int c = sub; c < C_; c += 32) d += rw[e * C_ + c] * sc[c];
      part[tid] = d;
    }
    __syncthreads();
    if (tid < E_) {
      float dot = 0.f;
      #pragma unroll
      for (int j = 0; j < 32; ++j) dot += part[tid * 32 + j];
      float inv = rg[tid] / sqrtf(rvar[tid] + 1e-5f);
      lg[tid] = (dot * (1.0f / HW_) + rb[tid]) * inv +
                (rbeta[tid] - rmean[tid] * inv);
    }
    __syncthreads();
    if (tid == 0) {
      float m = lg[0];
      for (int e = 1; e < E_; ++e) m = fmaxf(m, lg[e]);
      float pr[E_]; float s = 0.f;
      for (int e = 0; e < E_; ++e) { pr[e] = expf(lg[e] - m); s += pr[e]; }
      float invs = 1.0f / s;
      for (int e = 0; e < E_; ++e) pr[e] *= invs;
      int i1 = 0;
      for (int e = 1; e < E_; ++e) if (pr[e] > pr[i1]) i1 = e;
      int i2 = (i1 == 0) ? 1 : 0;
      for (int e = 0; e < E_; ++e) if (e != i1 && pr[e] > pr[i2]) i2 = e;
      float w = pr[i1] + pr[i2];
      float ga = pr[i1] / w, gb = pr[i2] / w;
      sel_e[2 * n] = i1; sel_e[2 * n + 1] = i2;
      sel_g[2 * n] = ga; sel_g[2 * n + 1] = gb;
      gsum[n] = ga + gb;
      s_i1 = i1; s_i2 = i2; s_g1 = ga; s_g2 = gb;
      atomicAdd(&f_acc[i1], 1.0f);
      atomicAdd(&f_acc[i2], 1.0f);
      for (int e = 0; e < E_; ++e) atomicAdd(&p_acc[e], pr[e]);
    }
    __syncthreads();
    int i1 = s_i1, i2 = s_i2; float ga = s_g1, gb = s_g2;
    for (int c = tid; c < C_; c += 256)
      K[(size_t)n * C_ + c] =
          ga * const2[i1 * C_ + c] + gb * const2[i2 * C_ + c];
  } else if (bid < N_ + 12) {
    // reduce rowmax partials: 3072 (e,c) entries
    int idx = (bid - N_) * 256 + tid;
    if (idx < E_ * C_) {
      float m = 0.f;
      #pragma unroll
      for (int t = 0; t < 24; ++t) m = fmaxf(m, rowmaxp[(size_t)idx * 24 + t]);
      rowmax[idx] = m;
    }
  } else {
    // thrmin[e] = min_o ( A!=0 ? -B/|A| : (B>=0 ? -inf : +inf) )
    float* red = sc;
    for (int e = 0; e < E_; ++e) {
      float m = INFINITY;
      for (int o = tid; o < HF_; o += 256) {
        float a = A[e * HF_ + o], b = Bc[e * HF_ + o];
        float thr = (a != 0.0f) ? (-b / fabsf(a))
                                : ((b >= 0.0f) ? -INFINITY : INFINITY);
        m = fminf(m, thr);
      }
      red[tid] = m;
      __syncthreads();
      for (int s = 128; s > 0; s >>= 1) {
        if (tid < s) red[tid] = fminf(red[tid], red[tid + s]);
        __syncthreads();
      }
      if (tid == 0) thrmin[e] = red[0];
      __syncthreads();
    }
  }
}

// ---------------------------------------------------------------------------
// K3: per (n,h): stage x, build spike lists for 28 (expert,w) tasks with
// certified bound-prune (nnz=-1), fused combine write. Wave-independent tasks.
// ---------------------------------------------------------------------------
__global__ __launch_bounds__(256) void k_lists(
    const float* __restrict__ x, const int* __restrict__ sel_e,
    const float* __restrict__ taus, const float* __restrict__ rowmax,
    const float* __restrict__ thrmin,
    const float* __restrict__ gsum, const float* __restrict__ K,
    float* __restrict__ out,
    int* __restrict__ nnzarr, unsigned short* __restrict__ list16) {
  __shared__ float xs[14 * 385];
  int bid = blockIdx.x, tid = threadIdx.x;
  int lane = tid & 63, wave = tid >> 6;
  int n = bid / 14, h = bid - n * 14;
  unsigned long long lmask = (1ull << lane) - 1ull;

  for (int idx = tid; idx < C_ * 7; idx += 256) {
    int c = idx / 7, wp = idx - c * 7;
    float2 v = *(const float2*)(x + ((size_t)(n * C_ + c) * 14 + h) * 14 + 2 * wp);
    xs[(2 * wp) * 385 + c]     = v.x;
    xs[(2 * wp + 1) * 385 + c] = v.y;
  }
  __syncthreads();

  for (int t = wave; t < 28; t += 4) {
    int k = t / 14, w = t - k * 14;
    int pair = 2 * n + k;
    int e = sel_e[pair];
    float tau = taus[e];
    const float* rme = rowmax + e * C_;
    int tw = pair * 196 + h * 14 + w;
    size_t lbase = (size_t)tw * LCAP;
    int nnz = 0;
    float myb = 0.f;
    #pragma unroll
    for (int cb = 0; cb < 6; ++cb) {
      int c = cb * 64 + lane;
      bool sp = (xs[w * 385 + c] / tau - 1.0f >= 0.0f);
      unsigned long long m = __ballot(sp);
      int pos = nnz + __popcll(m & lmask);
      if (sp) {
        if (pos < LCAP) list16[lbase + pos] = (unsigned short)c;
        myb += rme[c];
      }
      nnz += __popcll(m);
    }
    // wave-sum the bound
    #pragma unroll
    for (int off = 1; off < 64; off <<= 1) myb += __shfl_xor(myb, off, 64);
    if (lane == 0) {
      bool prune = (myb < thrmin[e] - 1e-4f);
      nnzarr[tw] = prune ? -1 : (nnz < LCAP ? nnz : LCAP);
    }
  }

  // fused combine: out = gsum*x + K
  float g = gsum[n];
  const float* Kn = K + (size_t)n * C_;
  for (int idx = tid; idx < C_ * 7; idx += 256) {
    int c = idx / 7, wp = idx - c * 7;
    float kc = Kn[c];
    float2 v;
    v.x = g * xs[(2 * wp) * 385 + c] + kc;
    v.y = g * xs[(2 * wp + 1) * 385 + c] + kc;
    *(float2*)(out + ((size_t)(n * C_ + c) * 14 + h) * 14 + 2 * wp) = v;
  }
}

// ---------------------------------------------------------------------------
// K4: gather — one wave per (pair,pos). 3 passes of 8 outputs/lane (spill-proof).
// ---------------------------------------------------------------------------
__global__ __launch_bounds__(256, 4) void k_gather(
    const __hip_bfloat16* __restrict__ w1t,
    const float* __restrict__ A, const float* __restrict__ Bc,
    const int* __restrict__ sel_e,
    const int* __restrict__ nnzarr, const unsigned short* __restrict__ list16,
    int* __restrict__ rec, int* __restrict__ rec_count) {
  int tw = blockIdx.x * 4 + (threadIdx.x >> 6);
  int lane = threadIdx.x & 63;
  int nnz = nnzarr[tw];
  if (nnz < 0) return;                          // certified: nothing fires
  int pair = tw / 196, pos = tw - pair * 196;
  int e = sel_e[pair];
  int lv = (int)list16[(size_t)tw * LCAP + lane];
  const uint4* wb = (const uint4*)(w1t + (size_t)e * C_ * HF_);  // 192 uint4/row

  #pragma unroll
  for (int pass = 0; pass < 3; ++pass) {
    const uint4* wbp = wb + pass * 64 + lane;
    float acc[8];
    #pragma unroll
    for (int q = 0; q < 8; ++q) acc[q] = 0.f;
    int j = 0;
    for (; j + 4 <= nnz; j += 4) {
      int c0 = __shfl(lv, j + 0);
      int c1 = __shfl(lv, j + 1);
      int c2 = __shfl(lv, j + 2);
      int c3 = __shfl(lv, j + 3);
      uint4 a = wbp[c0 * 192];
      uint4 b = wbp[c1 * 192];
      uint4 c = wbp[c2 * 192];
      uint4 d = wbp[c3 * 192];
      uint32_t ua[4] = {a.x, a.y, a.z, a.w};
      uint32_t ub[4] = {b.x, b.y, b.z, b.w};
      uint32_t uc[4] = {c.x, c.y, c.z, c.w};
      uint32_t ud[4] = {d.x, d.y, d.z, d.w};
      #pragma unroll
      for (int q = 0; q < 4; ++q) {
        acc[2 * q]     += __uint_as_float(ua[q] << 16) + __uint_as_float(ub[q] << 16) +
                          __uint_as_float(uc[q] << 16) + __uint_as_float(ud[q] << 16);
        acc[2 * q + 1] += __uint_as_float(ua[q] & 0xffff0000u) + __uint_as_float(ub[q] & 0xffff0000u) +
                          __uint_as_float(uc[q] & 0xffff0000u) + __uint_as_float(ud[q] & 0xffff0000u);
      }
    }
    for (; j < nnz; ++j) {
      int c0 = __shfl(lv, j);
      uint4 a = wbp[c0 * 192];
      uint32_t ua[4] = {a.x, a.y, a.z, a.w};
      #pragma unroll
      for (int q = 0; q < 4; ++q) {
        acc[2 * q]     += __uint_as_float(ua[q] << 16);
        acc[2 * q + 1] += __uint_as_float(ua[q] & 0xffff0000u);
      }
    }
    // threshold for my 8 outputs: o = (pass*64+lane)*8 + q
    int k2 = (pass * 64 + lane) * 2;
    float4 Av0 = ((const float4*)(A + e * HF_))[k2];
    float4 Av1 = ((const float4*)(A + e * HF_))[k2 + 1];
    float4 Bv0 = ((const float4*)(Bc + e * HF_))[k2];
    float4 Bv1 = ((const float4*)(Bc + e * HF_))[k2 + 1];
    float av[8] = {Av0.x, Av0.y, Av0.z, Av0.w, Av1.x, Av1.y, Av1.z, Av1.w};
    float bv[8] = {Bv0.x, Bv0.y, Bv0.z, Bv0.w, Bv1.x, Bv1.y, Bv1.z, Bv1.w};
    #pragma unroll
    for (int q = 0; q < 8; ++q) {
      if (av[q] * acc[q] + bv[q] >= 0.0f) {     // layer-2 spike (rare)
        int ridx = atomicAdd(rec_count, 1);
        if (ridx < REC_CAP) {
          rec[ridx * 3 + 0] = pair;
          rec[ridx * 3 + 1] = pos;
          rec[ridx * 3 + 2] = (pass * 64 + lane) * 8 + q;
        }
      }
    }
  }
}

// ---------------------------------------------------------------------------
// K5: apply rare records; write aux
// ---------------------------------------------------------------------------
__global__ void k_apply(const int* __restrict__ rec, const int* __restrict__ rec_count,
                        const int* __restrict__ sel_e, const float* __restrict__ sel_g,
                        const float* __restrict__ inv2v, const float* __restrict__ w2,
                        const float* f_acc, const float* p_acc,
                        float* __restrict__ out, float* aux_out) {
  int nrec = *rec_count;
  if (nrec > REC_CAP) nrec = REC_CAP;
  for (int r = blockIdx.x; r < nrec; r += gridDim.x) {
    int pair = rec[r * 3], pos = rec[r * 3 + 1], o = rec[r * 3 + 2];
    int n = pair >> 1;
    int e = sel_e[pair];
    float g = sel_g[pair];
    for (int c = threadIdx.x; c < C_; c += blockDim.x) {
      float wv = w2[(size_t)(e * C_ + c) * HF_ + o];
      atomicAdd(&out[(size_t)(n * C_ + c) * HW_ + pos],
                g * inv2v[e * C_ + c] * wv);
    }
  }
  if (blockIdx.x == 0 && threadIdx.x == 0) {
    float s = 0.f;
    for (int e = 0; e < E_; ++e)
      s += (f_acc[e] * (1.0f / N_)) * (p_acc[e] * (1.0f / N_));
    *aux_out = 0.01f * E_ * s;
  }
}

// ---------------------------------------------------------------------------
// Workspace layout (bytes), total ~17.1 MB
// ---------------------------------------------------------------------------
extern "C" void kernel_launch(void* const* d_in, const int* in_sizes, int n_in,
                              void* d_out, int out_size, void* d_ws, size_t ws_size,
                              hipStream_t stream) {
  const float* x       = (const float*)d_in[0];
  const float* rw      = (const float*)d_in[1];
  const float* rb      = (const float*)d_in[2];
  const float* r_gamma = (const float*)d_in[3];
  const float* r_beta  = (const float*)d_in[4];
  const float* r_mean  = (const float*)d_in[5];
  const float* r_var   = (const float*)d_in[6];
  const float* w1      = (const float*)d_in[7];
  const float* b1      = (const float*)d_in[8];
  const float* g1      = (const float*)d_in[9];
  const float* be1     = (const float*)d_in[10];
  const float* m1      = (const float*)d_in[11];
  const float* v1      = (const float*)d_in[12];
  const float* w2      = (const float*)d_in[13];
  const float* b2      = (const float*)d_in[14];
  const float* g2      = (const float*)d_in[15];
  const float* be2     = (const float*)d_in[16];
  const float* m2      = (const float*)d_in[17];
  const float* v2      = (const float*)d_in[18];
  const float* taus    = (const float*)d_in[19];
  float* out = (float*)d_out;

  char* ws = (char*)d_ws;
  int*   header = (int*)ws;
  float* f_acc  = (float*)ws + 8;
  float* p_acc  = (float*)ws + 16;
  float* cnt    = (float*)(ws + 256);
  int*   sel_e  = (int*)(ws + 196864);
  float* sel_g  = (float*)(ws + 197888);
  float* gsum   = (float*)(ws + 198912);
  float* K      = (float*)(ws + 199424);
  float* A      = (float*)(ws + 396032);
  float* Bc     = (float*)(ws + 445184);
  float* const2 = (float*)(ws + 494336);
  float* inv2v  = (float*)(ws + 506624);
  int*   rec    = (int*)(ws + 518912);
  __hip_bfloat16* w1t = (__hip_bfloat16*)(ws + 715520);
  int*   nnzarr = (int*)(ws + 10152704);
  unsigned short* list16 = (unsigned short*)(ws + 10353408);
  float* rowmaxp = (float*)(ws + 16775936);
  float* rowmax  = (float*)(ws + 17070848);
  float* thrmin  = (float*)(ws + 17083136);

  k_lifprep<<<LIFB + TRB + PRB, 256, 0, stream>>>(
      x, cnt, w1, w1t, b1, g1, be1, m1, v1, b2, g2, be2, m2, v2, taus,
      A, Bc, const2, inv2v, rowmaxp, header);
  k_router<<<N_ + 13, 256, 0, stream>>>(
      cnt, rw, rb, r_gamma, r_beta, r_mean, r_var, const2,
      rowmaxp, rowmax, A, Bc, thrmin,
      sel_e, sel_g, gsum, K, f_acc, p_acc);
  k_lists<<<NROW, 256, 0, stream>>>(
      x, sel_e, taus, rowmax, thrmin, gsum, K, out, nnzarr, list16);
  k_gather<<<NGT / 4, 256, 0, stream>>>(
      w1t, A, Bc, sel_e, nnzarr, list16, rec, header);
  k_apply<<<64, 256, 0, stream>>>(
      rec, header, sel_e, sel_g, inv2v, w2, f_acc, p_acc,
      out, out + (out_size - 1));
}